// Round 9
// baseline (469.387 us; speedup 1.0000x reference)
//
#include <hip/hip_runtime.h>

#define DIM 4096
#define KVDIM 1024
#define KVSTRIDE 2048
#define SEQ 2048
#define HEADS 32
#define HD 128

typedef __attribute__((ext_vector_type(8))) short bf16x8;
typedef __attribute__((ext_vector_type(4))) float f32x4;
typedef __attribute__((ext_vector_type(16))) float f32x16;
typedef __attribute__((ext_vector_type(4))) int int4v;

__device__ inline unsigned short f2bf(float f) {
    union { float f; unsigned int u; } v; v.f = f;
    unsigned int r = v.u + 0x7fffu + ((v.u >> 16) & 1u);
    return (unsigned short)(r >> 16);
}
__device__ inline float bf2f(unsigned short h) {
    union { unsigned int u; float f; } v; v.u = ((unsigned int)h) << 16;
    return v.f;
}

// async global->LDS, 16B per lane; LDS dest is wave-uniform base + lane*16
__device__ inline void gld16(const void* g, void* l) {
    __builtin_amdgcn_global_load_lds(
        (const __attribute__((address_space(1))) void*)g,
        (__attribute__((address_space(3))) void*)l, 16, 0, 0);
}

// v_cvt_pk_bf16_f32: lo=bf16(a), hi=bf16(b)
__device__ inline unsigned cvtpk(float a, float b) {
    unsigned r;
    asm("v_cvt_pk_bf16_f32 %0, %1, %2" : "=v"(r) : "v"(a), "v"(b));
    return r;
}

// ---------------- f32 -> bf16 conversion (vectorized) ----------------
__global__ void convert_f32_bf16(const float* __restrict__ in,
                                 unsigned short* __restrict__ out, int n) {
    int i = (blockIdx.x * blockDim.x + threadIdx.x) * 8;
    if (i >= n) return;
    const float4* p = (const float4*)(in + i);
    float4 a = p[0], b = p[1];
    bf16x8 o;
    o[0] = (short)f2bf(a.x); o[1] = (short)f2bf(a.y);
    o[2] = (short)f2bf(a.z); o[3] = (short)f2bf(a.w);
    o[4] = (short)f2bf(b.x); o[5] = (short)f2bf(b.y);
    o[6] = (short)f2bf(b.z); o[7] = (short)f2bf(b.w);
    *(bf16x8*)(out + i) = o;
}

// ---------------- RoPE cos/sin table: [SEQ][64] ----------------
__global__ void rope_table(float* __restrict__ cs, float* __restrict__ sn) {
    int i = blockIdx.x * blockDim.x + threadIdx.x;
    if (i >= SEQ * 64) return;
    int m = i >> 6, f = i & 63;
    float freq = expf(-(float)f * (9.210340371976184f / 64.0f));
    float ang = (float)m * freq;
    float s, c;
    sincosf(ang, &s, &c);
    cs[i] = c; sn[i] = s;
}

// ---------------- RoPE apply in-place (bf16), optional output scale ----------------
__global__ void rope_apply(unsigned short* __restrict__ q, int lppr, int stride, float scale,
                           const float* __restrict__ cs, const float* __restrict__ sn) {
    int i = blockIdx.x * blockDim.x + threadIdx.x;
    int m = i >> lppr;
    int p = i & ((1 << lppr) - 1);
    if (m >= SEQ) return;
    int f = p & 63;
    int col = ((p >> 6) << 7) + (f << 1);
    size_t idx = (size_t)m * stride + col;
    unsigned int u = *(const unsigned int*)&q[idx];
    float xr = bf2f((unsigned short)(u & 0xffffu));
    float xi = bf2f((unsigned short)(u >> 16));
    float c = cs[(m << 6) + f], s = sn[(m << 6) + f];
    float orr = (xr * c - xi * s) * scale;
    float oi  = (xr * s + xi * c) * scale;
    unsigned int w = ((unsigned int)f2bf(oi) << 16) | (unsigned int)f2bf(orr);
    *(unsigned int*)&q[idx] = w;
}

// ---------------- GEMM (m97 128x128): C = A @ W^T ----------------
template <bool OUT_BF16>
__global__ __launch_bounds__(256)
void gemm_bt(const unsigned short* __restrict__ A,
             const unsigned short* __restrict__ W,
             void* __restrict__ Cout, int M, int N, int K) {
    __shared__ __align__(16) unsigned short As[128 * 64];
    __shared__ __align__(16) unsigned short Ws[128 * 64];

    int nwg = gridDim.x * gridDim.y;
    int wg = blockIdx.y * gridDim.x + blockIdx.x;
    int cpx = nwg >> 3;
    wg = (wg & 7) * cpx + (wg >> 3);
    int bx = wg % gridDim.x, by = wg / gridDim.x;
    int brow = by * 128, bcol = bx * 128;

    int tid = threadIdx.x, lane = tid & 63, wid = tid >> 6;
    int wr = wid >> 1, wc = wid & 1, l15 = lane & 15, lq = lane >> 4;

    f32x4 acc[4][4] = {};

    for (int bk = 0; bk < K; bk += 64) {
        #pragma unroll
        for (int it = 0; it < 4; ++it) {
            int slot = it * 256 + wid * 64 + lane;
            int r = slot >> 3, g = slot & 7;
            gld16(&A[(size_t)(brow + r) * K + bk + ((g ^ (r & 7)) << 3)],
                  &As[(it * 256 + wid * 64) * 8]);
        }
        #pragma unroll
        for (int it = 0; it < 4; ++it) {
            int slot = it * 256 + wid * 64 + lane;
            int r = slot >> 3, g = slot & 7;
            gld16(&W[(size_t)(bcol + r) * K + bk + ((g ^ (r & 7)) << 3)],
                  &Ws[(it * 256 + wid * 64) * 8]);
        }
        __syncthreads();

        #pragma unroll
        for (int kk = 0; kk < 64; kk += 32) {
            int gb = (kk >> 3) + lq;
            bf16x8 af[4], bfr[4];
            #pragma unroll
            for (int m = 0; m < 4; ++m) {
                int r = wr * 64 + m * 16 + l15;
                af[m] = *(const bf16x8*)&As[r * 64 + ((gb ^ (r & 7)) << 3)];
            }
            #pragma unroll
            for (int n = 0; n < 4; ++n) {
                int r = wc * 64 + n * 16 + l15;
                bfr[n] = *(const bf16x8*)&Ws[r * 64 + ((gb ^ (r & 7)) << 3)];
            }
            #pragma unroll
            for (int m = 0; m < 4; ++m)
                #pragma unroll
                for (int n = 0; n < 4; ++n)
                    acc[m][n] = __builtin_amdgcn_mfma_f32_16x16x32_bf16(
                        af[m], bfr[n], acc[m][n], 0, 0, 0);
        }
        __syncthreads();
    }

    #pragma unroll
    for (int m = 0; m < 4; ++m) {
        #pragma unroll
        for (int n = 0; n < 4; ++n) {
            int row0 = brow + wr * 64 + m * 16 + lq * 4;
            int col = bcol + wc * 64 + n * 16 + l15;
            #pragma unroll
            for (int r = 0; r < 4; ++r) {
                if (OUT_BF16)
                    ((unsigned short*)Cout)[(size_t)(row0 + r) * N + col] = f2bf(acc[m][n][r]);
                else
                    ((float*)Cout)[(size_t)(row0 + r) * N + col] = acc[m][n][r];
            }
        }
    }
}

// ============ Flash attention: 8-wave KV-split (parallelism fix) ============
// 512 threads = 8 waves = 4 q-subtiles x 2 kv-halves. Wave (qsub, half)
// processes kv-tiles of parity `half`: per-wave serial work halves, wave
// count doubles (4096 waves = 4/SIMD), 2 blocks/CU (64KB LDS, VGPR<=128 via
// launch_bounds). Per iter: stage tile pair (all waves), barrier, each half
// computes its tile, barrier. Final: merge the two online-softmax states per
// q-row through LDS (m,l f32; O partial bf16). R4 compute core + R8 V layout.

__device__ __forceinline__ void softmax_pack(
    f32x16& s, f32x16* o_acc, float& m_run, float& l_run,
    int qw0, int kvs, int l31, int l5, bf16x8* pa) {
    if (kvs + 31 > qw0) {
        #pragma unroll
        for (int r = 0; r < 16; ++r) {
            int kv = kvs + (r & 3) + ((r >> 2) << 3) + l5 * 4;
            if (kv > qw0 + l31) s[r] = -1e30f;
        }
    }
    float mx = s[0];
    #pragma unroll
    for (int r = 1; r < 16; ++r) mx = fmaxf(mx, s[r]);
    mx = fmaxf(mx, __shfl_xor(mx, 32));
    bool need = mx > m_run + 8.0f;
    if (__any((int)need)) {
        float mn = fmaxf(m_run, mx);
        float al = exp2f(m_run - mn);
        m_run = mn;
        l_run *= al;
        #pragma unroll
        for (int r = 0; r < 16; ++r) {
            int qlr = (r & 3) + ((r >> 2) << 3) + l5 * 4;
            float alO = __shfl(al, qlr, 32);
            #pragma unroll
            for (int t32 = 0; t32 < 4; ++t32) o_acc[t32][r] *= alO;
        }
    }
    #pragma unroll
    for (int r = 0; r < 16; ++r) {
        float p = exp2f(s[r] - m_run);
        l_run += p;
        s[r] = p;
    }
    #pragma unroll
    for (int kk1 = 0; kk1 < 2; ++kk1) {
        unsigned u0 = cvtpk(s[kk1 * 8 + 0], s[kk1 * 8 + 1]);
        unsigned u1 = cvtpk(s[kk1 * 8 + 2], s[kk1 * 8 + 3]);
        unsigned u2 = cvtpk(s[kk1 * 8 + 4], s[kk1 * 8 + 5]);
        unsigned u3 = cvtpk(s[kk1 * 8 + 6], s[kk1 * 8 + 7]);
        unsigned t0 = (unsigned)__shfl_xor((int)(l5 ? u0 : u2), 32);
        unsigned t1 = (unsigned)__shfl_xor((int)(l5 ? u1 : u3), 32);
        int4v w;
        w.x = (int)(l5 ? t0 : u0);
        w.y = (int)(l5 ? t1 : u1);
        w.z = (int)(l5 ? u2 : t0);
        w.w = (int)(l5 ? u3 : t1);
        pa[kk1] = __builtin_bit_cast(bf16x8, w);
    }
}

__global__ __launch_bounds__(512, 4)
void attn_kernel(const unsigned short* __restrict__ Q,
                 const unsigned short* __restrict__ KV,
                 unsigned short* __restrict__ O) {
    __shared__ __align__(16) unsigned short smem[32768];   // 64 KB

    unsigned short* ks0 = smem;             // 16 KB: K tile (even)
    unsigned short* ks1 = smem + 8192;      // 16 KB: K tile (odd)
    unsigned short* vt0 = smem + 16384;     // 16 KB: V^T tile (even)
    unsigned short* vt1 = smem + 24576;     // 16 KB: V^T tile (odd)

    int h = blockIdx.x;
    int yy = (gridDim.y - 1) - blockIdx.y;   // LPT: longest blocks first
    int q0 = yy * 128;
    int kvh = h >> 2;
    int tid = threadIdx.x, lane = tid & 63, wid = tid >> 6;
    int qsub = wid & 3, half = wid >> 2;
    int l31 = lane & 31, l5 = lane >> 5;
    int qw0 = q0 + qsub * 32;

    bf16x8 qf[8];
    #pragma unroll
    for (int k8 = 0; k8 < 8; ++k8)
        qf[k8] = *(const bf16x8*)&Q[(size_t)(qw0 + l31) * DIM + h * HD + k8 * 16 + l5 * 8];

    f32x16 o_acc[4] = {};
    float m_run = -1e30f, l_run = 0.0f;

    // V staging: thread stages 2 kv-rows x 8 d's per tile
    int k2 = tid >> 4;            // 0..31 -> kv rows k2*2, k2*2+1
    int d0 = (tid & 15) * 8;      // 0..120
    int vsub = (k2 & 3) * 2;      // short offset within granule
    int vg = k2 >> 2;             // natural granule 0..7

    const unsigned short* Kb = KV + kvh * HD;
    const unsigned short* Vb = KV + KVDIM + kvh * HD;

    unsigned short* myks = half ? ks1 : ks0;
    unsigned short* myvt = half ? vt1 : vt0;

    int np = yy + 1;   // tile pairs; ntiles = 2*np (always even)
    for (int i = 0; i < np; ++i) {
        // ---- stage K tiles 2i (->ks0) and 2i+1 (->ks1), all 8 waves ----
        #pragma unroll
        for (int tt = 0; tt < 2; ++tt) {
            int kvb = (2 * i + tt) * 64;
            unsigned short* kd = tt ? ks1 : ks0;
            #pragma unroll
            for (int it = 0; it < 2; ++it) {
                int slot = it * 512 + tid;
                int r = slot >> 4, g = slot & 15;
                gld16(&Kb[(size_t)(kvb + r) * KVSTRIDE + ((g ^ (r & 7)) << 3)],
                      &kd[(it * 512 + wid * 64) * 8]);
            }
        }
        // ---- stage V tiles (reg transpose, XOR'd b32 writes, 2-way free) ----
        #pragma unroll
        for (int tt = 0; tt < 2; ++tt) {
            int kvb = (2 * i + tt) * 64;
            unsigned short* vd = tt ? vt1 : vt0;
            bf16x8 va = *(const bf16x8*)&Vb[(size_t)(kvb + k2 * 2) * KVSTRIDE + d0];
            bf16x8 vb = *(const bf16x8*)&Vb[(size_t)(kvb + k2 * 2 + 1) * KVSTRIDE + d0];
            #pragma unroll
            for (int j = 0; j < 8; ++j) {
                int row = d0 + j;
                int swz = ((row >> 3) ^ row) & 7;
                unsigned w = ((unsigned)(unsigned short)vb[j] << 16) |
                             (unsigned)(unsigned short)va[j];
                *(unsigned*)&vd[row * 64 + ((vg ^ swz) << 3) + vsub] = w;
            }
        }
        __syncthreads();

        // ---- compute own-parity tile ----
        int kv0 = (2 * i + half) * 64;
        if (kv0 <= qw0 + 31) {
            #pragma unroll
            for (int sub = 0; sub < 2; ++sub) {
                int kvs = kv0 + sub * 32;
                if (kvs > qw0 + 31) continue;
                f32x16 s = {};
                __builtin_amdgcn_s_setprio(1);
                #pragma unroll
                for (int k8 = 0; k8 < 8; ++k8) {
                    int r = sub * 32 + l31;
                    bf16x8 kf = *(const bf16x8*)&myks[r * 128 + (((k8 * 2 + l5) ^ (r & 7)) << 3)];
                    s = __builtin_amdgcn_mfma_f32_32x32x16_bf16(kf, qf[k8], s, 0, 0, 0);
                }
                __builtin_amdgcn_s_setprio(0);
                bf16x8 pa[2];
                softmax_pack(s, o_acc, m_run, l_run, qw0, kvs, l31, l5, pa);
                __builtin_amdgcn_s_setprio(1);
                #pragma unroll
                for (int t32 = 0; t32 < 4; ++t32) {
                    int d = t32 * 32 + l31;
                    int swz = ((d >> 3) ^ d) & 7;
                    #pragma unroll
                    for (int kk1 = 0; kk1 < 2; ++kk1) {
                        int g = sub * 4 + kk1 * 2 + l5;
                        int4v w = *(const int4v*)&myvt[d * 64 + ((g ^ swz) << 3)];
                        o_acc[t32] = __builtin_amdgcn_mfma_f32_32x32x16_bf16(
                            pa[kk1], __builtin_bit_cast(bf16x8, w), o_acc[t32], 0, 0, 0);
                    }
                }
                __builtin_amdgcn_s_setprio(0);
            }
        }
        __syncthreads();
    }

    // ---- merge the two kv-half states (overlay on dead K/V LDS) ----
    float* part_m = (float*)smem;                    // [4][64]
    float* part_l = (float*)(smem + 512);            // [4][64]
    unsigned* part_o = (unsigned*)(smem + 1024);     // [4][4][64][8] u32 (bf16x2)

    if (half == 1) {
        part_m[qsub * 64 + lane] = m_run;
        part_l[qsub * 64 + lane] = l_run;
        #pragma unroll
        for (int t32 = 0; t32 < 4; ++t32) {
            unsigned* po = &part_o[((qsub * 4 + t32) * 64 + lane) * 8];
            #pragma unroll
            for (int p = 0; p < 8; ++p)
                po[p] = cvtpk(o_acc[t32][2 * p], o_acc[t32][2 * p + 1]);
        }
    }
    __syncthreads();
    if (half == 0) {
        float m1 = part_m[qsub * 64 + lane];
        float l1 = part_l[qsub * 64 + lane];
        float mm = fmaxf(m_run, m1);
        float a0 = exp2f(m_run - mm), a1 = exp2f(m1 - mm);
        float lm = l_run * a0 + l1 * a1;
        float l_tot = lm + __shfl_xor(lm, 32);
        float rinv = __builtin_amdgcn_rcpf(l_tot);
        #pragma unroll
        for (int r = 0; r < 16; ++r) {
            int qlr = (r & 3) + ((r >> 2) << 3) + l5 * 4;
            float A0 = __shfl(a0, qlr, 32);
            float A1 = __shfl(a1, qlr, 32);
            float rl = __shfl(rinv, qlr, 32);
            #pragma unroll
            for (int t32 = 0; t32 < 4; ++t32) {
                unsigned u = part_o[((qsub * 4 + t32) * 64 + lane) * 8 + (r >> 1)];
                float o1 = bf2f((unsigned short)((r & 1) ? (u >> 16) : (u & 0xffffu)));
                float om = o_acc[t32][r] * A0 + o1 * A1;
                O[(size_t)(qw0 + qlr) * DIM + h * HD + t32 * 32 + l31] = f2bf(om * rl);
            }
        }
    }
}

// ---------------- host ----------------
extern "C" void kernel_launch(void* const* d_in, const int* in_sizes, int n_in,
                              void* d_out, int out_size, void* d_ws, size_t ws_size,
                              hipStream_t stream) {
    const float* x  = (const float*)d_in[0];
    const float* wq = (const float*)d_in[2];
    const float* wk = (const float*)d_in[3];
    const float* wv = (const float*)d_in[4];
    const float* wo = (const float*)d_in[5];
    float* out = (float*)d_out;

    char* ws = (char*)d_ws;
    unsigned short* xb  = (unsigned short*)(ws);               // 16 MiB
    unsigned short* qb  = (unsigned short*)(ws + 16777216);    // 16 MiB
    unsigned short* kvb = (unsigned short*)(ws + 33554432);    //  8 MiB (K|V, stride 2048)
    unsigned short* ab  = (unsigned short*)(ws + 41943040);    // 16 MiB
    float* cs = (float*)(ws + 58720256);
    float* sn = cs + SEQ * 64;
    unsigned short* wscratch = (unsigned short*)d_out;         // weight staging
    unsigned short* wob = (unsigned short*)(ws);               // after attn: xb dead

    const float SCALE2 = 0.08838834764831845f * 1.4426950408889634f;

    convert_f32_bf16<<<SEQ * DIM / 2048, 256, 0, stream>>>(x, xb, SEQ * DIM);
    rope_table<<<SEQ * 64 / 256, 256, 0, stream>>>(cs, sn);

    convert_f32_bf16<<<DIM * DIM / 2048, 256, 0, stream>>>(wq, wscratch, DIM * DIM);
    gemm_bt<true><<<dim3(DIM / 128, SEQ / 128), 256, 0, stream>>>(xb, wscratch, qb, SEQ, DIM, DIM);

    convert_f32_bf16<<<KVDIM * DIM / 2048, 256, 0, stream>>>(wk, wscratch, KVDIM * DIM);
    convert_f32_bf16<<<KVDIM * DIM / 2048, 256, 0, stream>>>(wv, wscratch + (size_t)KVDIM * DIM, KVDIM * DIM);
    gemm_bt<true><<<dim3(KVSTRIDE / 128, SEQ / 128), 256, 0, stream>>>(xb, wscratch, kvb, SEQ, KVSTRIDE, DIM);

    rope_apply<<<SEQ * (DIM / 2) / 256, 256, 0, stream>>>(qb, 11, DIM, SCALE2, cs, sn);
    rope_apply<<<SEQ * (KVDIM / 2) / 256, 256, 0, stream>>>(kvb, 9, KVSTRIDE, 1.0f, cs, sn);

    attn_kernel<<<dim3(HEADS, 16), 512, 0, stream>>>(qb, kvb, ab);

    convert_f32_bf16<<<DIM * DIM / 2048, 256, 0, stream>>>(wo, wob, DIM * DIM);
    gemm_bt<false><<<dim3(DIM / 128, SEQ / 128), 256, 0, stream>>>(ab, wob, out, SEQ, DIM, DIM);
}